// Round 1
// 18046.054 us; speedup vs baseline: 1.1130x; 1.1130x over previous
//
#include <hip/hip_runtime.h>

// BasicLSTM on MI355X (gfx950) — persistent-kernel recurrent phase.
//
// Structure per layer: chunked input GEMM (X@Wx+b -> G, fp16) as before, but
// the per-timestep work is now ONE persistent kernel per chunk (lstm_chunk):
// 128 co-resident blocks run all CH steps with a software grid barrier
// between steps. Block g owns 8 hidden cols x 4 gates (2 MFMA n-tiles:
// {i,j} and {f,o}); Wh B-fragments live in REGISTERS (64 VGPR/wave, loaded
// once per chunk), the cell state c lives in registers across the chunk,
// and G is prefetched into the accumulator init BEFORE the barrier.
// K=1024 is split 4 ways across waves; partials reduced via 32 KB LDS.
//
// Barrier safety: ring is a 2-slot double buffer. Step t reads slot (t-1)&1
// and writes slot t&1; slot t&1 was last READ at step t-1, whose loads
// complete (vmcnt drain at __syncthreads) before that block arrives at the
// barrier separating t-1 from t -> one barrier per step suffices.
// Visibility: leader does __threadfence (L2 writeback) before arriving and
// __threadfence (invalidate) after release, covering sibling waves (shared
// per-CU L1 / per-XCD L2). Atomics are agent-scope acquire/release.
//
// Workspace (bytes):
//   WpH0 @ 0        : Wh layer0, per-block frag layout   8,388,608
//   WpH1 @ 8388608  : Wh layer1                          8,388,608
//   WpX  @ 16777216 : 1024x4096 fp16 std pack (per phase)8,388,608
//   ring @ 25165824 : 2 layers x 2 slots x 64x1024 fp16    524,288
//   cb   @ 25690112 : 2x64x1024 fp32                       524,288
//   bar  @ 26214400 : grid-barrier state                     1,024
//   Gc   @ 26215424 : CHUNK x 64x4096 fp16             CHUNK*524,288

typedef _Float16 half8 __attribute__((ext_vector_type(8)));
typedef float    f32x4 __attribute__((ext_vector_type(4)));

#define SEQ 512
#define BATCH 64
#define HID 1024
#define NBLK 128
#define SLSZ 65536  // BATCH*HID

// ---- fallback: write zeros over all of d_out (guarantees >=1 launch) -------
__global__ void zero_out(float* __restrict__ out) {
    size_t i = (size_t)blockIdx.x * blockDim.x + threadIdx.x;
    ((f32x4*)out)[i] = f32x4{0.f, 0.f, 0.f, 0.f};
}

// ---- standard pack: 1024x4096 fp32 -> fp16 B-frags (for gemm_in) -----------
// B-frag 16x16x32: lane L holds B[k = kt*32 + (L>>4)*8 + j][n = nt*16 + (L&15)]
__global__ void pack1(const float* __restrict__ src, _Float16* __restrict__ dst) {
    int nt   = blockIdx.x;        // 0..255
    int ktg  = blockIdx.y;        // 0..7
    int lane = threadIdx.x & 63;
    int wave = threadIdx.x >> 6;
    int kt   = ktg * 4 + wave;    // 0..31
    int k0 = kt * 32 + (lane >> 4) * 8;
    int n  = nt * 16 + (lane & 15);
    half8 v;
#pragma unroll
    for (int j = 0; j < 8; ++j)
        v[j] = (_Float16)src[(size_t)(k0 + j) * 4096 + n];
    *(half8*)(dst + ((size_t)(nt * 32 + kt) * 64 + lane) * 8) = v;
}

// ---- recurrent-weight pack for lstm_chunk ----------------------------------
// Block g owns hid cols g*8..g*8+7. Two n-tiles per block:
//   tau=0: cols {i: hbase..+7, j: hbase..+7}, tau=1: {f..., o...}
// lane's tile column: col = (tau*2 + (c16>>3))*1024 + g*8 + (c16&7)
// packed offset = (((g*2+tau)*32 + kt)*64 + lane)*8 + j
__global__ void pack_wh(const float* __restrict__ src, _Float16* __restrict__ dst) {
    int g    = blockIdx.x;        // 0..127
    int ktg  = blockIdx.y;        // 0..7
    int lane = threadIdx.x & 63;
    int wave = threadIdx.x >> 6;
    int kt   = ktg * 4 + wave;    // 0..31
    int c16  = lane & 15;
    int k0   = kt * 32 + (lane >> 4) * 8;
#pragma unroll
    for (int tau = 0; tau < 2; ++tau) {
        int col = (tau * 2 + (c16 >> 3)) * 1024 + g * 8 + (c16 & 7);
        half8 v;
#pragma unroll
        for (int j = 0; j < 8; ++j)
            v[j] = (_Float16)src[(size_t)(k0 + j) * 4096 + col];
        *(half8*)(dst + ((size_t)((g * 2 + tau) * 32 + kt) * 64 + lane) * 8) = v;
    }
}

// ---- c0 -> cb ---------------------------------------------------------------
__global__ void copy_f4(const float* __restrict__ src, float* __restrict__ dst) {
    int i = blockIdx.x * blockDim.x + threadIdx.x;
    ((f32x4*)dst)[i] = ((const f32x4*)src)[i];
}

// ---- barrier state init -----------------------------------------------------
__global__ void init_bar(int* __restrict__ bar) {
    bar[threadIdx.x] = 0;   // zero the whole 1 KiB slot
}

// ---- chunk input GEMM: G = A(fp32) @ Wpacked + bias -> fp16 (unchanged) ----
__global__ __launch_bounds__(256) void gemm_in(
    const float* __restrict__ A, const _Float16* __restrict__ Bp,
    const float* __restrict__ bias, _Float16* __restrict__ Gout)
{
    int lane = threadIdx.x & 63;
    int wave = threadIdx.x >> 6;
    int wm = wave & 1, wn = wave >> 1;
    int m0 = blockIdx.x * 128 + wm * 64;
    int n0 = blockIdx.y * 128 + wn * 64;
    int col = lane & 15, quad = lane >> 4;
    f32x4 acc[4][4] = {};
    const float*    Arow  = A + (size_t)(m0 + col) * 1024 + quad * 8;
    const _Float16* Bbase = Bp + (size_t)(n0 >> 4) * 16384 + (size_t)lane * 8;
    for (int kt = 0; kt < 32; ++kt) {
        half8 a[4], b[4];
#pragma unroll
        for (int i = 0; i < 4; ++i) {
            const float* p = Arow + (size_t)i * 16 * 1024 + kt * 32;
            f32x4 v0 = *(const f32x4*)(p);
            f32x4 v1 = *(const f32x4*)(p + 4);
            a[i][0] = (_Float16)v0[0]; a[i][1] = (_Float16)v0[1];
            a[i][2] = (_Float16)v0[2]; a[i][3] = (_Float16)v0[3];
            a[i][4] = (_Float16)v1[0]; a[i][5] = (_Float16)v1[1];
            a[i][6] = (_Float16)v1[2]; a[i][7] = (_Float16)v1[3];
        }
#pragma unroll
        for (int j = 0; j < 4; ++j)
            b[j] = *(const half8*)(Bbase + (size_t)j * 16384 + kt * 512);
#pragma unroll
        for (int i = 0; i < 4; ++i)
#pragma unroll
            for (int j = 0; j < 4; ++j)
                acc[i][j] = __builtin_amdgcn_mfma_f32_16x16x32_f16(a[i], b[j], acc[i][j], 0, 0, 0);
    }
#pragma unroll
    for (int j = 0; j < 4; ++j) {
        int n = n0 + j * 16 + col;
        float bv = bias[n];
#pragma unroll
        for (int i = 0; i < 4; ++i)
#pragma unroll
            for (int r = 0; r < 4; ++r) {
                int m = m0 + i * 16 + quad * 4 + r;
                Gout[(size_t)m * 4096 + n] = (_Float16)(acc[i][j][r] + bv);
            }
    }
}

// ---- software grid barrier (128 co-resident blocks) ------------------------
__device__ __forceinline__ void grid_barrier(int* __restrict__ bar) {
    __syncthreads();  // all waves drain vmcnt: step's loads+stores complete
    if (threadIdx.x == 0) {
        __threadfence();  // release: write back this XCD's L2 (h,ring stores)
        int myg = __hip_atomic_load(bar + 1, __ATOMIC_ACQUIRE, __HIP_MEMORY_SCOPE_AGENT);
        int prev = __hip_atomic_fetch_add(bar, 1, __ATOMIC_ACQ_REL, __HIP_MEMORY_SCOPE_AGENT);
        if (prev == NBLK - 1) {
            __hip_atomic_store(bar, 0, __ATOMIC_RELAXED, __HIP_MEMORY_SCOPE_AGENT);
            __hip_atomic_fetch_add(bar + 1, 1, __ATOMIC_RELEASE, __HIP_MEMORY_SCOPE_AGENT);
        } else {
            while (__hip_atomic_load(bar + 1, __ATOMIC_RELAXED, __HIP_MEMORY_SCOPE_AGENT) == myg)
                __builtin_amdgcn_s_sleep(1);
        }
        __threadfence();  // acquire: invalidate L1/L2 so next reads are fresh
    }
    __syncthreads();
}

// ---- persistent recurrent kernel: CH timesteps, one grid barrier/step ------
__global__ __launch_bounds__(256, 1) void lstm_chunk(
    const _Float16* __restrict__ Whp, const _Float16* __restrict__ Gc,
    const float* __restrict__ h0l, _Float16* __restrict__ ringl,
    float* __restrict__ cbl, float* __restrict__ out,
    float* __restrict__ lasth, float* __restrict__ lastc,
    int t0, int nsteps, int* __restrict__ bar)
{
    const int lane = threadIdx.x & 63;
    const int wave = threadIdx.x >> 6;
    const int g = blockIdx.x;
    const int c16 = lane & 15, quad = lane >> 4;
    const int hbase = g * 8;
    const int hcol = hbase + (c16 & 7);
    const bool owner = (c16 < 8);

    __shared__ f32x4 red[4][4][2][64];  // [kwave][m][tau][lane], 32 KiB

    // Wh fragments resident in registers: breg[tau][i] for kt = wave*8+i
    half8 breg[2][8];
#pragma unroll
    for (int tau = 0; tau < 2; ++tau)
#pragma unroll
        for (int i = 0; i < 8; ++i)
            breg[tau][i] = *(const half8*)(Whp +
                ((size_t)((g * 2 + tau) * 32 + wave * 8 + i) * 64 + lane) * 8);

    // cell state for rows b = wave*16 + quad*4 + r, hidden col hcol
    float creg[4];
#pragma unroll
    for (int r = 0; r < 4; ++r)
        creg[r] = cbl[(size_t)(wave * 16 + quad * 4 + r) * HID + hcol];

    for (int tl = 0; tl < nsteps; ++tl) {
        const int t = t0 + tl;
        const _Float16* Gt = Gc + (size_t)tl * 4 * SLSZ;

        // acc init: fold G (input gates + bias) into wave's own m-tile,
        // issued BEFORE the barrier (G is static for the whole kernel).
        // Static indices only (rule #20: no runtime-indexed vector arrays).
        f32x4 acc[4][2];
#pragma unroll
        for (int m = 0; m < 4; ++m)
#pragma unroll
            for (int tau = 0; tau < 2; ++tau) {
                if (m == wave) {
                    const int colG = (tau * 2 + (c16 >> 3)) * 1024 + hcol;
                    f32x4 v;
#pragma unroll
                    for (int r = 0; r < 4; ++r)
                        v[r] = (float)Gt[(size_t)(m * 16 + quad * 4 + r) * 4096 + colG];
                    acc[m][tau] = v;
                } else {
                    acc[m][tau] = f32x4{0.f, 0.f, 0.f, 0.f};
                }
            }

        if (tl > 0) grid_barrier(bar);

        // recurrent GEMM, K split by wave: kt = wave*8 + i
        const _Float16* hp16 = ringl + (size_t)((t - 1) & 1) * SLSZ;
        if (t == 0) {
#pragma unroll 2
            for (int i = 0; i < 8; ++i) {
                const int k0 = (wave * 8 + i) * 32 + quad * 8;
                half8 a[4];
#pragma unroll
                for (int m = 0; m < 4; ++m) {
                    const float* p = h0l + (size_t)(m * 16 + c16) * HID + k0;
                    f32x4 v0 = *(const f32x4*)p, v1 = *(const f32x4*)(p + 4);
                    a[m][0] = (_Float16)v0[0]; a[m][1] = (_Float16)v0[1];
                    a[m][2] = (_Float16)v0[2]; a[m][3] = (_Float16)v0[3];
                    a[m][4] = (_Float16)v1[0]; a[m][5] = (_Float16)v1[1];
                    a[m][6] = (_Float16)v1[2]; a[m][7] = (_Float16)v1[3];
                }
#pragma unroll
                for (int m = 0; m < 4; ++m)
#pragma unroll
                    for (int tau = 0; tau < 2; ++tau)
                        acc[m][tau] = __builtin_amdgcn_mfma_f32_16x16x32_f16(
                            a[m], breg[tau][i], acc[m][tau], 0, 0, 0);
            }
        } else {
#pragma unroll
            for (int i = 0; i < 8; ++i) {
                const int k0 = (wave * 8 + i) * 32 + quad * 8;
                half8 a[4];
#pragma unroll
                for (int m = 0; m < 4; ++m)
                    a[m] = *(const half8*)(hp16 + (size_t)(m * 16 + c16) * HID + k0);
#pragma unroll
                for (int m = 0; m < 4; ++m)
#pragma unroll
                    for (int tau = 0; tau < 2; ++tau)
                        acc[m][tau] = __builtin_amdgcn_mfma_f32_16x16x32_f16(
                            a[m], breg[tau][i], acc[m][tau], 0, 0, 0);
            }
        }

        // cross-wave K reduction: wave w finalizes m-tile w
#pragma unroll
        for (int m = 0; m < 4; ++m)
#pragma unroll
            for (int tau = 0; tau < 2; ++tau)
                red[wave][m][tau][lane] = acc[m][tau];
        __syncthreads();
        f32x4 fin[2];
#pragma unroll
        for (int tau = 0; tau < 2; ++tau) {
            f32x4 s = red[0][wave][tau][lane];
#pragma unroll
            for (int v = 1; v < 4; ++v) s += red[v][wave][tau][lane];
            fin[tau] = s;
        }

        // LSTM cell. tau0 cols: c16<8 -> gate i, c16>=8 -> gate j;
        // tau1: f / o. shfl_xor(8) exchanges the pairs; both halves keep
        // consistent creg copies, only c16<8 lanes write.
        _Float16* rw = ringl + (size_t)(t & 1) * SLSZ;
        float* outp = out + (size_t)t * SLSZ;
#pragma unroll
        for (int r = 0; r < 4; ++r) {
            float v0 = fin[0][r], v1 = fin[1][r];
            float x0 = __shfl_xor(v0, 8);
            float x1 = __shfl_xor(v1, 8);
            float gi = owner ? v0 : x0;
            float gj = owner ? x0 : v0;
            float gf = owner ? v1 : x1;
            float go = owner ? x1 : v1;
            float iv = 1.f / (1.f + __expf(-gi));
            float jv = tanhf(gj);
            float fv = 1.f / (1.f + __expf(-gf));
            float ov = 1.f / (1.f + __expf(-go));
            float cn = creg[r] * fv + iv * jv;
            float hn = tanhf(cn) * ov;
            creg[r] = cn;
            if (owner) {
                size_t idx = (size_t)(wave * 16 + quad * 4 + r) * HID + hcol;
                rw[idx] = (_Float16)hn;
                outp[idx] = hn;
                if (t == SEQ - 1) { lasth[idx] = hn; lastc[idx] = cn; }
            }
        }
        // next iteration's grid_barrier releases these writes
    }

    // persist cell state for the next chunk
    if (owner) {
#pragma unroll
        for (int r = 0; r < 4; ++r)
            cbl[(size_t)(wave * 16 + quad * 4 + r) * HID + hcol] = creg[r];
    }
}

extern "C" void kernel_launch(void* const* d_in, const int* in_sizes, int n_in,
                              void* d_out, int out_size, void* d_ws, size_t ws_size,
                              hipStream_t stream) {
    const float* X  = (const float*)d_in[0];
    const float* h0 = (const float*)d_in[1];
    const float* c0 = (const float*)d_in[2];
    const float* W  = (const float*)d_in[3];
    const float* bb = (const float*)d_in[4];
    float* out = (float*)d_out;
    char* ws = (char*)d_ws;

    const size_t FIXED = 26215424ULL;   // 26,214,400 + 1 KiB barrier slot
    int CH = 0;
    const int tiers[4] = {32, 16, 8, 4};
    for (int i = 0; i < 4; ++i)
        if (ws_size >= FIXED + (size_t)tiers[i] * 524288ULL) { CH = tiers[i]; break; }
    if (CH == 0) {
        zero_out<<<dim3(33024), 256, 0, stream>>>(out);
        return;
    }

    _Float16* WpH0 = (_Float16*)(ws + 0);
    _Float16* WpH1 = (_Float16*)(ws + 8388608);
    _Float16* WpX  = (_Float16*)(ws + 16777216);
    _Float16* ring = (_Float16*)(ws + 25165824);   // 2 layers x 2 slots x SLSZ
    float*    cb   = (float*)(ws + 25690112);
    int*      bar  = (int*)(ws + 26214400);
    _Float16* Gc   = (_Float16*)(ws + 26215424);

    const size_t MSTRIDE = 2048ULL * 4096ULL;      // per-layer W block (floats)
    const size_t SL = (size_t)BATCH * HID;         // 65,536
    const size_t FO = (size_t)SEQ * SL;            // 33,554,432
    const int MC = CH * BATCH;
    const int NCHUNK = SEQ / CH;

    pack_wh<<<dim3(NBLK, 8), 256, 0, stream>>>(W + 1024 * 4096, WpH0);
    pack_wh<<<dim3(NBLK, 8), 256, 0, stream>>>(W + MSTRIDE + 1024 * 4096, WpH1);
    copy_f4<<<dim3(128), 256, 0, stream>>>(c0, cb);
    init_bar<<<dim3(1), 256, 0, stream>>>(bar);

    for (int layer = 0; layer < 2; ++layer) {
        pack1<<<dim3(256, 8), 256, 0, stream>>>(W + (size_t)layer * MSTRIDE, WpX);
        const _Float16* Whp = layer ? WpH1 : WpH0;
        const float* bias = bb + (size_t)layer * 4096;
        float* cbl = cb + (size_t)layer * SL;
        _Float16* ringl = ring + (size_t)layer * 2 * SL;
        const float* h0l = h0 + (size_t)layer * SL;
        float* lasth = out + FO + (size_t)layer * SL;
        float* lastc = out + FO + 2 * SL + (size_t)layer * SL;
        // layer 0 reads X; layer 1 reads layer-0 h history stored in out (fp32)
        const float* Asrc = layer ? out : X;
        for (int chunk = 0; chunk < NCHUNK; ++chunk) {
            gemm_in<<<dim3(MC / 128, 32), 256, 0, stream>>>(
                Asrc + (size_t)chunk * MC * 1024, WpX, bias, Gc);
            lstm_chunk<<<dim3(NBLK), 256, 0, stream>>>(
                Whp, Gc, h0l, ringl, cbl, out, lasth, lastc,
                chunk * CH, CH, bar);
        }
    }
}

// Round 2
// 14446.202 us; speedup vs baseline: 1.3904x; 1.2492x over previous
//
#include <hip/hip_runtime.h>

// BasicLSTM on MI355X (gfx950) — fused two-layer pipelined persistent kernel.
//
// Barrier-step s: layer0 computes t=s (gates = G0[s] + h0[s-1]@Wh0), layer1
// computes t=s-1 (gates = b1 + h0[s-1]@Wx1 + h1[s-2]@Wh1, K=2048 in-kernel).
// One relaxed-atomic grid barrier per step (513 total vs 1024 before), with
// exactly one release fence + one acquire fence per block per step.
// All four weight matrices register/LDS-free resident: Wh0/Wx1/Wh1 B-frags
// live in 192 VGPRs per wave (loaded once per chunk); Wx0 std-pack feeds the
// chunked input GEMM. Cell states c0,c1 live in registers across each chunk.
//
// Ring safety (2-slot double buffers, one barrier/step): at step s,
//   L0 writes ring0[s&1], L0+L1 read ring0[(s-1)&1]  (different slot);
//   L1 writes ring1[(s-1)&1], reads ring1[s&1]       (different slot);
// slot written at step s was last READ at step s-1; readers' loads complete
// before barrier arrival (release fence waits vmcnt(0)) -> WAR safe.
//
// Workspace (bytes):
//   WpX  @ 0        : Wx0 std pack (gemm_in)      8,388,608
//   WhR0 @ 8388608  : Wh0 per-block frag pack     8,388,608
//   WxR1 @ 16777216 : Wx1 per-block frag pack     8,388,608
//   WhR1 @ 25165824 : Wh1 per-block frag pack     8,388,608
//   ring @ 33554432 : 2 layers x 2 slots x 64x1024 fp16   524,288
//   cb   @ 34078720 : 2x64x1024 fp32                      524,288
//   Gc   @ 34603008 : CHUNK x 64x4096 fp16          CHUNK*524,288
// FIXED = 34,603,008; CH=16 needs 42,991,616 (== known-good ws floor).
// Barrier state is a __device__ global (not in ws).

typedef _Float16 half8 __attribute__((ext_vector_type(8)));
typedef float    f32x4 __attribute__((ext_vector_type(4)));

#define SEQ 512
#define BATCH 64
#define HID 1024
#define NBLK 128
#define SLSZ 65536  // BATCH*HID

__device__ int g_bar[64];   // [0] = arrive counter (monotonic), [32] = release flag

__global__ void init_bar_k() { if (threadIdx.x < 64) g_bar[threadIdx.x] = 0; }

// ---- fallback: write zeros over all of d_out (guarantees >=1 launch) -------
__global__ void zero_out(float* __restrict__ out) {
    size_t i = (size_t)blockIdx.x * blockDim.x + threadIdx.x;
    ((f32x4*)out)[i] = f32x4{0.f, 0.f, 0.f, 0.f};
}

// ---- standard pack: 1024x4096 fp32 -> fp16 B-frags (for gemm_in) -----------
__global__ void pack1(const float* __restrict__ src, _Float16* __restrict__ dst) {
    int nt   = blockIdx.x;        // 0..255
    int ktg  = blockIdx.y;        // 0..7
    int lane = threadIdx.x & 63;
    int wave = threadIdx.x >> 6;
    int kt   = ktg * 4 + wave;    // 0..31
    int k0 = kt * 32 + (lane >> 4) * 8;
    int n  = nt * 16 + (lane & 15);
    half8 v;
#pragma unroll
    for (int j = 0; j < 8; ++j)
        v[j] = (_Float16)src[(size_t)(k0 + j) * 4096 + n];
    *(half8*)(dst + ((size_t)(nt * 32 + kt) * 64 + lane) * 8) = v;
}

// ---- per-block frag pack for lstm_fused ------------------------------------
// Block g owns hid cols g*8..g*8+7; tau=0 covers gates {i,j}, tau=1 {f,o}.
// lane column: col = (tau*2 + (c16>>3))*1024 + g*8 + (c16&7)
__global__ void pack_wh(const float* __restrict__ src, _Float16* __restrict__ dst) {
    int g    = blockIdx.x;        // 0..127
    int ktg  = blockIdx.y;        // 0..7
    int lane = threadIdx.x & 63;
    int wave = threadIdx.x >> 6;
    int kt   = ktg * 4 + wave;    // 0..31
    int c16  = lane & 15;
    int k0   = kt * 32 + (lane >> 4) * 8;
#pragma unroll
    for (int tau = 0; tau < 2; ++tau) {
        int col = (tau * 2 + (c16 >> 3)) * 1024 + g * 8 + (c16 & 7);
        half8 v;
#pragma unroll
        for (int j = 0; j < 8; ++j)
            v[j] = (_Float16)src[(size_t)(k0 + j) * 4096 + col];
        *(half8*)(dst + ((size_t)((g * 2 + tau) * 32 + kt) * 64 + lane) * 8) = v;
    }
}

// ---- c0 -> cb ---------------------------------------------------------------
__global__ void copy_f4(const float* __restrict__ src, float* __restrict__ dst) {
    int i = blockIdx.x * blockDim.x + threadIdx.x;
    ((f32x4*)dst)[i] = ((const f32x4*)src)[i];
}

// ---- chunk input GEMM: G = A(fp32) @ Wpacked + bias -> fp16 (layer 0 only) -
__global__ __launch_bounds__(256) void gemm_in(
    const float* __restrict__ A, const _Float16* __restrict__ Bp,
    const float* __restrict__ bias, _Float16* __restrict__ Gout)
{
    int lane = threadIdx.x & 63;
    int wave = threadIdx.x >> 6;
    int wm = wave & 1, wn = wave >> 1;
    int m0 = blockIdx.x * 128 + wm * 64;
    int n0 = blockIdx.y * 128 + wn * 64;
    int col = lane & 15, quad = lane >> 4;
    f32x4 acc[4][4] = {};
    const float*    Arow  = A + (size_t)(m0 + col) * 1024 + quad * 8;
    const _Float16* Bbase = Bp + (size_t)(n0 >> 4) * 16384 + (size_t)lane * 8;
    for (int kt = 0; kt < 32; ++kt) {
        half8 a[4], b[4];
#pragma unroll
        for (int i = 0; i < 4; ++i) {
            const float* p = Arow + (size_t)i * 16 * 1024 + kt * 32;
            f32x4 v0 = *(const f32x4*)(p);
            f32x4 v1 = *(const f32x4*)(p + 4);
            a[i][0] = (_Float16)v0[0]; a[i][1] = (_Float16)v0[1];
            a[i][2] = (_Float16)v0[2]; a[i][3] = (_Float16)v0[3];
            a[i][4] = (_Float16)v1[0]; a[i][5] = (_Float16)v1[1];
            a[i][6] = (_Float16)v1[2]; a[i][7] = (_Float16)v1[3];
        }
#pragma unroll
        for (int j = 0; j < 4; ++j)
            b[j] = *(const half8*)(Bbase + (size_t)j * 16384 + kt * 512);
#pragma unroll
        for (int i = 0; i < 4; ++i)
#pragma unroll
            for (int j = 0; j < 4; ++j)
                acc[i][j] = __builtin_amdgcn_mfma_f32_16x16x32_f16(a[i], b[j], acc[i][j], 0, 0, 0);
    }
#pragma unroll
    for (int j = 0; j < 4; ++j) {
        int n = n0 + j * 16 + col;
        float bv = bias[n];
#pragma unroll
        for (int i = 0; i < 4; ++i)
#pragma unroll
            for (int r = 0; r < 4; ++r) {
                int m = m0 + i * 16 + quad * 4 + r;
                Gout[(size_t)m * 4096 + n] = (_Float16)(acc[i][j][r] + bv);
            }
    }
}

// ---- minimal-fence grid barrier (monotonic counters, no reset) -------------
__device__ __forceinline__ void grid_barrier(int n) {
    __syncthreads();  // also drains this block's loads/stores ordering w.r.t. waves
    if (threadIdx.x == 0) {
        __builtin_amdgcn_fence(__ATOMIC_RELEASE, "agent");  // waitcnt + wbL2, once
        int v = __hip_atomic_fetch_add(&g_bar[0], 1, __ATOMIC_RELAXED, __HIP_MEMORY_SCOPE_AGENT);
        if (v == n * NBLK - 1) {
            __hip_atomic_store(&g_bar[32], n, __ATOMIC_RELAXED, __HIP_MEMORY_SCOPE_AGENT);
        } else {
            while (__hip_atomic_load(&g_bar[32], __ATOMIC_RELAXED, __HIP_MEMORY_SCOPE_AGENT) < n)
                __builtin_amdgcn_s_sleep(1);
        }
        __builtin_amdgcn_fence(__ATOMIC_ACQUIRE, "agent");  // invL2, once
    }
    __syncthreads();
}

__device__ __forceinline__ half8 cvt_row(const float* p) {
    f32x4 v0 = *(const f32x4*)p, v1 = *(const f32x4*)(p + 4);
    half8 a;
    a[0] = (_Float16)v0[0]; a[1] = (_Float16)v0[1];
    a[2] = (_Float16)v0[2]; a[3] = (_Float16)v0[3];
    a[4] = (_Float16)v1[0]; a[5] = (_Float16)v1[1];
    a[6] = (_Float16)v1[2]; a[7] = (_Float16)v1[3];
    return a;
}

// one K=1024 pass (8 kt per wave) into acc, B-frags from registers
template <bool F32SRC>
__device__ __forceinline__ void gemm_pass(
    f32x4 (&acc)[4][2], const void* src, const half8 (&breg)[2][8],
    int wave, int c16, int quad)
{
#pragma unroll
    for (int i = 0; i < 8; ++i) {
        const int k0 = (wave * 8 + i) * 32 + quad * 8;
        half8 a[4];
#pragma unroll
        for (int m = 0; m < 4; ++m) {
            if constexpr (F32SRC)
                a[m] = cvt_row((const float*)src + (size_t)(m * 16 + c16) * HID + k0);
            else
                a[m] = *(const half8*)((const _Float16*)src + (size_t)(m * 16 + c16) * HID + k0);
        }
#pragma unroll
        for (int m = 0; m < 4; ++m)
#pragma unroll
            for (int tau = 0; tau < 2; ++tau)
                acc[m][tau] = __builtin_amdgcn_mfma_f32_16x16x32_f16(
                    a[m], breg[tau][i], acc[m][tau], 0, 0, 0);
    }
}

// ---- fused two-layer pipelined persistent kernel ---------------------------
__global__ __launch_bounds__(256, 1) void lstm_fused(
    const _Float16* __restrict__ WhR0, const _Float16* __restrict__ WxR1,
    const _Float16* __restrict__ WhR1, const _Float16* __restrict__ Gc,
    const float* __restrict__ hinit, _Float16* __restrict__ ring,
    float* __restrict__ cb, float* __restrict__ out,
    const float* __restrict__ bias1, int t0, int nsteps, int nbar0)
{
    const int lane = threadIdx.x & 63;
    const int wave = threadIdx.x >> 6;
    const int g = blockIdx.x;
    const int c16 = lane & 15, quad = lane >> 4;
    const int hcol = g * 8 + (c16 & 7);
    const bool owner = (c16 < 8);
    const int rbase = wave * 16 + quad * 4;   // 4 batch rows of own m-tile

    __shared__ f32x4 red0[3][4][2][64];  // off-diagonal partials, 24 KiB
    __shared__ f32x4 red1[3][4][2][64];

    _Float16* ring0 = ring;
    _Float16* ring1 = ring + 2 * SLSZ;
    const size_t FO = (size_t)SEQ * SLSZ;

    // B-frags resident in registers (192 VGPR): kt = wave*8 + i
    half8 bh0[2][8], bx1[2][8], bh1[2][8];
#pragma unroll
    for (int tau = 0; tau < 2; ++tau)
#pragma unroll
        for (int i = 0; i < 8; ++i) {
            size_t off = ((size_t)((g * 2 + tau) * 32 + wave * 8 + i) * 64 + lane) * 8;
            bh0[tau][i] = *(const half8*)(WhR0 + off);
            bx1[tau][i] = *(const half8*)(WxR1 + off);
            bh1[tau][i] = *(const half8*)(WhR1 + off);
        }

    float bv1[2];
#pragma unroll
    for (int tau = 0; tau < 2; ++tau)
        bv1[tau] = bias1[(tau * 2 + (c16 >> 3)) * 1024 + hcol];

    float creg0[4], creg1[4];
#pragma unroll
    for (int r = 0; r < 4; ++r) {
        creg0[r] = cb[(size_t)(rbase + r) * HID + hcol];
        creg1[r] = cb[SLSZ + (size_t)(rbase + r) * HID + hcol];
    }

    const int colG0 = (c16 >> 3) * 1024 + hcol;  // tau=0 column in [0,4096)

    for (int tl = 0; tl < nsteps; ++tl) {
        const int s  = t0 + tl;   // layer-0 step
        const int t1 = s - 1;     // layer-1 step
        const bool do0 = (s < SEQ);
        const bool do1 = (t1 >= 0);

        // G0 prefetch + acc0 init BEFORE the barrier (Gc static per launch;
        // release fence's waitcnt overlaps the load latency with arrival)
        f32x4 acc0[4][2];
#pragma unroll
        for (int m = 0; m < 4; ++m)
#pragma unroll
            for (int tau = 0; tau < 2; ++tau)
                acc0[m][tau] = f32x4{0.f, 0.f, 0.f, 0.f};
        if (do0) {
            const _Float16* Gt = Gc + (size_t)tl * 4 * SLSZ;
#pragma unroll
            for (int tau = 0; tau < 2; ++tau) {
                f32x4 v;
#pragma unroll
                for (int r = 0; r < 4; ++r)
                    v[r] = (float)Gt[(size_t)(rbase + r) * 4096 + tau * 2048 + colG0];
#pragma unroll
                for (int m = 0; m < 4; ++m)
                    if (m == wave) acc0[m][tau] = v;
            }
        }

        if (tl > 0) grid_barrier(nbar0 + tl);

        // ---------------- layer 0: t = s ----------------
        if (do0) {
            if (s == 0)
                gemm_pass<true>(acc0, hinit, bh0, wave, c16, quad);
            else
                gemm_pass<false>(acc0, ring0 + (size_t)((s - 1) & 1) * SLSZ, bh0,
                                 wave, c16, quad);
#pragma unroll
            for (int m = 0; m < 4; ++m)
                if (m != wave) {
                    int slot = wave - (wave > m ? 1 : 0);
#pragma unroll
                    for (int tau = 0; tau < 2; ++tau)
                        red0[slot][m][tau][lane] = acc0[m][tau];
                }
        }
        f32x4 own0[2];
        own0[0] = acc0[0][0]; own0[1] = acc0[0][1];
#pragma unroll
        for (int m = 1; m < 4; ++m)
            if (wave == m) { own0[0] = acc0[m][0]; own0[1] = acc0[m][1]; }

        // ---------------- layer 1: t = s-1 (K=2048) ----------------
        f32x4 acc1[4][2];
#pragma unroll
        for (int m = 0; m < 4; ++m)
#pragma unroll
            for (int tau = 0; tau < 2; ++tau)
                acc1[m][tau] = f32x4{0.f, 0.f, 0.f, 0.f};
#pragma unroll
        for (int tau = 0; tau < 2; ++tau)
#pragma unroll
            for (int m = 0; m < 4; ++m)
                if (m == wave)
                    acc1[m][tau] = f32x4{bv1[tau], bv1[tau], bv1[tau], bv1[tau]};
        if (do1) {
            // x-input: h0[t1] (written by layer0 at step t1, barrier-separated)
            gemm_pass<false>(acc1, ring0 + (size_t)(t1 & 1) * SLSZ, bx1,
                             wave, c16, quad);
            // recurrent: h1[t1-1]
            if (t1 == 0)
                gemm_pass<true>(acc1, hinit + SLSZ, bh1, wave, c16, quad);
            else
                gemm_pass<false>(acc1, ring1 + (size_t)((t1 - 1) & 1) * SLSZ, bh1,
                                 wave, c16, quad);
#pragma unroll
            for (int m = 0; m < 4; ++m)
                if (m != wave) {
                    int slot = wave - (wave > m ? 1 : 0);
#pragma unroll
                    for (int tau = 0; tau < 2; ++tau)
                        red1[slot][m][tau][lane] = acc1[m][tau];
                }
        }
        f32x4 own1[2];
        own1[0] = acc1[0][0]; own1[1] = acc1[0][1];
#pragma unroll
        for (int m = 1; m < 4; ++m)
            if (wave == m) { own1[0] = acc1[m][0]; own1[1] = acc1[m][1]; }

        __syncthreads();

        // ---------------- epilogues ----------------
        if (do0) {
            f32x4 fin[2];
#pragma unroll
            for (int tau = 0; tau < 2; ++tau) {
                f32x4 ssum = own0[tau];
#pragma unroll
                for (int v = 0; v < 3; ++v) ssum += red0[v][wave][tau][lane];
                fin[tau] = ssum;
            }
            _Float16* rw = ring0 + (size_t)(s & 1) * SLSZ;
#pragma unroll
            for (int r = 0; r < 4; ++r) {
                float v0 = fin[0][r], v1 = fin[1][r];
                float x0 = __shfl_xor(v0, 8), x1 = __shfl_xor(v1, 8);
                float gi = owner ? v0 : x0, gj = owner ? x0 : v0;
                float gf = owner ? v1 : x1, go = owner ? x1 : v1;
                float iv = 1.f / (1.f + __expf(-gi));
                float jv = tanhf(gj);
                float fv = 1.f / (1.f + __expf(-gf));
                float ov = 1.f / (1.f + __expf(-go));
                float cn = creg0[r] * fv + iv * jv;
                float hn = tanhf(cn) * ov;
                creg0[r] = cn;
                if (owner) {
                    size_t idx = (size_t)(rbase + r) * HID + hcol;
                    rw[idx] = (_Float16)hn;
                    if (s == SEQ - 1) {
                        out[FO + idx] = hn;              // last_hidden layer0
                        out[FO + 2 * SLSZ + idx] = cn;   // last_cell   layer0
                    }
                }
            }
        }
        if (do1) {
            f32x4 fin[2];
#pragma unroll
            for (int tau = 0; tau < 2; ++tau) {
                f32x4 ssum = own1[tau];
#pragma unroll
                for (int v = 0; v < 3; ++v) ssum += red1[v][wave][tau][lane];
                fin[tau] = ssum;
            }
            _Float16* rw = ring1 + (size_t)(t1 & 1) * SLSZ;
            float* outp = out + (size_t)t1 * SLSZ;
#pragma unroll
            for (int r = 0; r < 4; ++r) {
                float v0 = fin[0][r], v1 = fin[1][r];
                float x0 = __shfl_xor(v0, 8), x1 = __shfl_xor(v1, 8);
                float gi = owner ? v0 : x0, gj = owner ? x0 : v0;
                float gf = owner ? v1 : x1, go = owner ? x1 : v1;
                float iv = 1.f / (1.f + __expf(-gi));
                float jv = tanhf(gj);
                float fv = 1.f / (1.f + __expf(-gf));
                float ov = 1.f / (1.f + __expf(-go));
                float cn = creg1[r] * fv + iv * jv;
                float hn = tanhf(cn) * ov;
                creg1[r] = cn;
                if (owner) {
                    size_t idx = (size_t)(rbase + r) * HID + hcol;
                    rw[idx] = (_Float16)hn;
                    outp[idx] = hn;                       // final output
                    if (t1 == SEQ - 1) {
                        out[FO + SLSZ + idx] = hn;        // last_hidden layer1
                        out[FO + 3 * SLSZ + idx] = cn;    // last_cell   layer1
                    }
                }
            }
        }
    }

    // persist cell state for the next chunk
    if (owner) {
#pragma unroll
        for (int r = 0; r < 4; ++r) {
            cb[(size_t)(rbase + r) * HID + hcol] = creg0[r];
            cb[SLSZ + (size_t)(rbase + r) * HID + hcol] = creg1[r];
        }
    }
}

extern "C" void kernel_launch(void* const* d_in, const int* in_sizes, int n_in,
                              void* d_out, int out_size, void* d_ws, size_t ws_size,
                              hipStream_t stream) {
    const float* X  = (const float*)d_in[0];
    const float* h0 = (const float*)d_in[1];
    const float* c0 = (const float*)d_in[2];
    const float* W  = (const float*)d_in[3];
    const float* bb = (const float*)d_in[4];
    float* out = (float*)d_out;
    char* ws = (char*)d_ws;

    const size_t FIXED = 34603008ULL;
    int CH = 0;
    const int tiers[4] = {32, 16, 8, 4};
    for (int i = 0; i < 4; ++i)
        if (ws_size >= FIXED + (size_t)tiers[i] * 524288ULL) { CH = tiers[i]; break; }
    if (CH == 0) {
        zero_out<<<dim3(33024), 256, 0, stream>>>(out);
        return;
    }

    _Float16* WpX  = (_Float16*)(ws + 0);
    _Float16* WhR0 = (_Float16*)(ws + 8388608);
    _Float16* WxR1 = (_Float16*)(ws + 16777216);
    _Float16* WhR1 = (_Float16*)(ws + 25165824);
    _Float16* ring = (_Float16*)(ws + 33554432);
    float*    cb   = (float*)(ws + 34078720);
    _Float16* Gc   = (_Float16*)(ws + 34603008);

    const size_t MSTRIDE = 2048ULL * 4096ULL;   // per-layer W block (floats)
    const int MC = CH * BATCH;
    const int NCHUNK = SEQ / CH;

    pack1<<<dim3(256, 8), 256, 0, stream>>>(W, WpX);                          // Wx0 (std)
    pack_wh<<<dim3(NBLK, 8), 256, 0, stream>>>(W + 1024 * 4096, WhR0);        // Wh0
    pack_wh<<<dim3(NBLK, 8), 256, 0, stream>>>(W + MSTRIDE, WxR1);            // Wx1
    pack_wh<<<dim3(NBLK, 8), 256, 0, stream>>>(W + MSTRIDE + 1024 * 4096, WhR1); // Wh1
    copy_f4<<<dim3(128), 256, 0, stream>>>(c0, cb);
    init_bar_k<<<dim3(1), 64, 0, stream>>>();

    int nbar = 0;
    for (int chunk = 0; chunk < NCHUNK; ++chunk) {
        gemm_in<<<dim3(MC / 128, 32), 256, 0, stream>>>(
            X + (size_t)chunk * MC * 1024, WpX, bb, Gc);
        int nsteps = CH + (chunk == NCHUNK - 1 ? 1 : 0);
        lstm_fused<<<dim3(NBLK), 256, 0, stream>>>(
            WhR0, WxR1, WhR1, Gc, h0, ring, cb, out, bb + 4096,
            chunk * CH, nsteps, nbar);
        nbar += nsteps - 1;
    }
}

// Round 3
// 12822.350 us; speedup vs baseline: 1.5665x; 1.1266x over previous
//
#include <hip/hip_runtime.h>

// BasicLSTM on MI355X (gfx950) — fused two-layer persistent kernel,
// fence-free MALL-coherent h exchange + hierarchical grid barrier.
//
// Barrier-step s: layer0 computes t=s, layer1 computes t=s-1 (pipelined).
// h ring buffers are accessed ONLY via agent-scope relaxed atomics
// (loads: u64, stores: paired u32) -> cross-XCD coherent at the Infinity
// Cache, so NO buffer_wbl2/buffer_inv fences are needed anywhere; L2 stays
// warm for Gc and weight reads. The grid barrier is hierarchical
// (8 group counters -> 1 global counter -> 1 release flag, each on its own
// 256B line) to kill same-line RMW/poll contention.
//
// Pass fusion: layer0 (Wh0) and layer1-x (Wx1) share the same A = h0[s-1];
// one A-load feeds both accumulators. Wh1 lives in LDS (64 KiB) to keep
// arch-VGPR pressure under control (bh0+bx1 = 128 VGPR register-resident).
//
// Ring WAR safety (2 slots, one barrier/step): slot written at step s was
// last read at step s-1; readers' loads drain (vmcnt0 at __syncthreads)
// before barrier arrival.
//
// Workspace (bytes):
//   WpX  @ 0        : Wx0 std pack (gemm_in)      8,388,608
//   WhR0 @ 8388608  : Wh0 per-block frag pack     8,388,608
//   WxR1 @ 16777216 : Wx1 per-block frag pack     8,388,608
//   WhR1 @ 25165824 : Wh1 per-block frag pack     8,388,608
//   ring @ 33554432 : 2 layers x 2 slots x 64x1024 fp16   524,288
//   cb   @ 34078720 : 2x64x1024 fp32                      524,288
//   Gc   @ 34603008 : CHUNK x 64x4096 fp16          CHUNK*524,288
// FIXED = 34,603,008; CH=16 -> 42,991,616 (known-good ws floor).

typedef _Float16 half8 __attribute__((ext_vector_type(8)));
typedef float    f32x4 __attribute__((ext_vector_type(4)));
typedef unsigned long long u64;
typedef unsigned int u32;

#define SEQ 512
#define BATCH 64
#define HID 1024
#define NBLK 128
#define SLSZ 65536  // BATCH*HID

// sync state: group counters at [0,64,..,448], global counter [576], release [704]
__device__ int g_sync[1024];

__global__ void init_bar_k() {
    for (int i = threadIdx.x; i < 1024; i += 256) g_sync[i] = 0;
}

// ---- fallback: write zeros over all of d_out (guarantees >=1 launch) -------
__global__ void zero_out(float* __restrict__ out) {
    size_t i = (size_t)blockIdx.x * blockDim.x + threadIdx.x;
    ((f32x4*)out)[i] = f32x4{0.f, 0.f, 0.f, 0.f};
}

// ---- standard pack: 1024x4096 fp32 -> fp16 B-frags (for gemm_in) -----------
__global__ void pack1(const float* __restrict__ src, _Float16* __restrict__ dst) {
    int nt   = blockIdx.x;        // 0..255
    int ktg  = blockIdx.y;        // 0..7
    int lane = threadIdx.x & 63;
    int wave = threadIdx.x >> 6;
    int kt   = ktg * 4 + wave;    // 0..31
    int k0 = kt * 32 + (lane >> 4) * 8;
    int n  = nt * 16 + (lane & 15);
    half8 v;
#pragma unroll
    for (int j = 0; j < 8; ++j)
        v[j] = (_Float16)src[(size_t)(k0 + j) * 4096 + n];
    *(half8*)(dst + ((size_t)(nt * 32 + kt) * 64 + lane) * 8) = v;
}

// ---- per-block frag pack for lstm_fused ------------------------------------
// Block g owns hid cols g*8..g*8+7; tau=0 covers gates {i,j}, tau=1 {f,o}.
__global__ void pack_wh(const float* __restrict__ src, _Float16* __restrict__ dst) {
    int g    = blockIdx.x;        // 0..127
    int ktg  = blockIdx.y;        // 0..7
    int lane = threadIdx.x & 63;
    int wave = threadIdx.x >> 6;
    int kt   = ktg * 4 + wave;    // 0..31
    int c16  = lane & 15;
    int k0   = kt * 32 + (lane >> 4) * 8;
#pragma unroll
    for (int tau = 0; tau < 2; ++tau) {
        int col = (tau * 2 + (c16 >> 3)) * 1024 + g * 8 + (c16 & 7);
        half8 v;
#pragma unroll
        for (int j = 0; j < 8; ++j)
            v[j] = (_Float16)src[(size_t)(k0 + j) * 4096 + col];
        *(half8*)(dst + ((size_t)((g * 2 + tau) * 32 + kt) * 64 + lane) * 8) = v;
    }
}

// ---- c0 -> cb ---------------------------------------------------------------
__global__ void copy_f4(const float* __restrict__ src, float* __restrict__ dst) {
    int i = blockIdx.x * blockDim.x + threadIdx.x;
    ((f32x4*)dst)[i] = ((const f32x4*)src)[i];
}

// ---- chunk input GEMM: G = A(fp32) @ Wpacked + bias -> fp16 (layer 0 only) -
__global__ __launch_bounds__(256) void gemm_in(
    const float* __restrict__ A, const _Float16* __restrict__ Bp,
    const float* __restrict__ bias, _Float16* __restrict__ Gout)
{
    int lane = threadIdx.x & 63;
    int wave = threadIdx.x >> 6;
    int wm = wave & 1, wn = wave >> 1;
    int m0 = blockIdx.x * 128 + wm * 64;
    int n0 = blockIdx.y * 128 + wn * 64;
    int col = lane & 15, quad = lane >> 4;
    f32x4 acc[4][4] = {};
    const float*    Arow  = A + (size_t)(m0 + col) * 1024 + quad * 8;
    const _Float16* Bbase = Bp + (size_t)(n0 >> 4) * 16384 + (size_t)lane * 8;
    for (int kt = 0; kt < 32; ++kt) {
        half8 a[4], b[4];
#pragma unroll
        for (int i = 0; i < 4; ++i) {
            const float* p = Arow + (size_t)i * 16 * 1024 + kt * 32;
            f32x4 v0 = *(const f32x4*)(p);
            f32x4 v1 = *(const f32x4*)(p + 4);
            a[i][0] = (_Float16)v0[0]; a[i][1] = (_Float16)v0[1];
            a[i][2] = (_Float16)v0[2]; a[i][3] = (_Float16)v0[3];
            a[i][4] = (_Float16)v1[0]; a[i][5] = (_Float16)v1[1];
            a[i][6] = (_Float16)v1[2]; a[i][7] = (_Float16)v1[3];
        }
#pragma unroll
        for (int j = 0; j < 4; ++j)
            b[j] = *(const half8*)(Bbase + (size_t)j * 16384 + kt * 512);
#pragma unroll
        for (int i = 0; i < 4; ++i)
#pragma unroll
            for (int j = 0; j < 4; ++j)
                acc[i][j] = __builtin_amdgcn_mfma_f32_16x16x32_f16(a[i], b[j], acc[i][j], 0, 0, 0);
    }
#pragma unroll
    for (int j = 0; j < 4; ++j) {
        int n = n0 + j * 16 + col;
        float bv = bias[n];
#pragma unroll
        for (int i = 0; i < 4; ++i)
#pragma unroll
            for (int r = 0; r < 4; ++r) {
                int m = m0 + i * 16 + quad * 4 + r;
                Gout[(size_t)m * 4096 + n] = (_Float16)(acc[i][j][r] + bv);
            }
    }
}

// ---- fence-free hierarchical grid barrier ----------------------------------
// Monotonic counters, no reset, no cache-maintenance fences: all cross-block
// data goes through agent-coherent atomics, so vmcnt(0) at __syncthreads
// (compiler-emitted before s_barrier) is the only ordering needed.
__device__ __forceinline__ void grid_barrier(int n) {
    __syncthreads();
    if (threadIdx.x == 0) {
        const int grp = (int)(blockIdx.x & 7);
        int v = __hip_atomic_fetch_add(&g_sync[grp * 64], 1,
                                       __ATOMIC_RELAXED, __HIP_MEMORY_SCOPE_AGENT);
        if (v == n * 16 - 1) {      // last of my 16-block group this episode
            int gv = __hip_atomic_fetch_add(&g_sync[576], 1,
                                            __ATOMIC_RELAXED, __HIP_MEMORY_SCOPE_AGENT);
            if (gv == n * 8 - 1)    // last group
                __hip_atomic_store(&g_sync[704], n,
                                   __ATOMIC_RELAXED, __HIP_MEMORY_SCOPE_AGENT);
        }
        while (__hip_atomic_load(&g_sync[704],
                                 __ATOMIC_RELAXED, __HIP_MEMORY_SCOPE_AGENT) < n)
            __builtin_amdgcn_s_sleep(1);
    }
    __syncthreads();
}

// ---- coherent (cross-XCD) helpers ------------------------------------------
__device__ __forceinline__ half8 cload8(const _Float16* p) {
    union { half8 h; u64 u[2]; } x;
    x.u[0] = __hip_atomic_load((const u64*)p, __ATOMIC_RELAXED, __HIP_MEMORY_SCOPE_AGENT);
    x.u[1] = __hip_atomic_load((const u64*)p + 1, __ATOMIC_RELAXED, __HIP_MEMORY_SCOPE_AGENT);
    return x.h;
}

__device__ __forceinline__ half8 cvt_row(const float* p) {
    f32x4 v0 = *(const f32x4*)p, v1 = *(const f32x4*)(p + 4);
    half8 a;
    a[0] = (_Float16)v0[0]; a[1] = (_Float16)v0[1];
    a[2] = (_Float16)v0[2]; a[3] = (_Float16)v0[3];
    a[4] = (_Float16)v1[0]; a[5] = (_Float16)v1[1];
    a[6] = (_Float16)v1[2]; a[7] = (_Float16)v1[3];
    return a;
}

// ---- fused pass A: A = h0-source, feeds acc0 (bh0) and/or acc1 (bx1) -------
template <bool F32, bool DO0, bool DO1>
__device__ __forceinline__ void passA(
    f32x4 (&acc0)[4][2], f32x4 (&acc1)[4][2], const void* src,
    const half8 (&b0)[2][8], const half8 (&b1)[2][8],
    int wave, int c16, int quad)
{
#pragma unroll
    for (int i = 0; i < 8; ++i) {
        const int k0 = (wave * 8 + i) * 32 + quad * 8;
        half8 a[4];
#pragma unroll
        for (int m = 0; m < 4; ++m) {
            if constexpr (F32)
                a[m] = cvt_row((const float*)src + (size_t)(m * 16 + c16) * HID + k0);
            else
                a[m] = cload8((const _Float16*)src + (size_t)(m * 16 + c16) * HID + k0);
        }
#pragma unroll
        for (int m = 0; m < 4; ++m) {
            if constexpr (DO0) {
                acc0[m][0] = __builtin_amdgcn_mfma_f32_16x16x32_f16(a[m], b0[0][i], acc0[m][0], 0, 0, 0);
                acc0[m][1] = __builtin_amdgcn_mfma_f32_16x16x32_f16(a[m], b0[1][i], acc0[m][1], 0, 0, 0);
            }
            if constexpr (DO1) {
                acc1[m][0] = __builtin_amdgcn_mfma_f32_16x16x32_f16(a[m], b1[0][i], acc1[m][0], 0, 0, 0);
                acc1[m][1] = __builtin_amdgcn_mfma_f32_16x16x32_f16(a[m], b1[1][i], acc1[m][1], 0, 0, 0);
            }
        }
    }
}

// ---- pass B: A = h1-source, B = Wh1 from LDS, feeds acc1 -------------------
template <bool F32>
__device__ __forceinline__ void passB(
    f32x4 (&acc1)[4][2], const void* src, const half8* smw,
    int wave, int c16, int quad, int lane)
{
#pragma unroll
    for (int i = 0; i < 8; ++i) {
        const int k0 = (wave * 8 + i) * 32 + quad * 8;
        half8 a[4];
#pragma unroll
        for (int m = 0; m < 4; ++m) {
            if constexpr (F32)
                a[m] = cvt_row((const float*)src + (size_t)(m * 16 + c16) * HID + k0);
            else
                a[m] = cload8((const _Float16*)src + (size_t)(m * 16 + c16) * HID + k0);
        }
        half8 bw0 = smw[(size_t)((0 * 32 + wave * 8 + i) * 64 + lane)];
        half8 bw1 = smw[(size_t)((1 * 32 + wave * 8 + i) * 64 + lane)];
#pragma unroll
        for (int m = 0; m < 4; ++m) {
            acc1[m][0] = __builtin_amdgcn_mfma_f32_16x16x32_f16(a[m], bw0, acc1[m][0], 0, 0, 0);
            acc1[m][1] = __builtin_amdgcn_mfma_f32_16x16x32_f16(a[m], bw1, acc1[m][1], 0, 0, 0);
        }
    }
}

// ---- LSTM cell epilogue: gates -> (c,h), coherent packed ring store --------
__device__ __forceinline__ void cell_epilogue(
    const f32x4 (&fin)[2], float (&creg)[4], _Float16* rw, float* outp,
    float* lh, float* lc, int rbase, int hcol, int c16, bool owner)
{
#pragma unroll
    for (int r = 0; r < 4; ++r) {
        float v0 = fin[0][r], v1 = fin[1][r];
        float x0 = __shfl_xor(v0, 8), x1 = __shfl_xor(v1, 8);
        float gi = owner ? v0 : x0, gj = owner ? x0 : v0;
        float gf = owner ? v1 : x1, go = owner ? x1 : v1;
        float iv = 1.f / (1.f + __expf(-gi));
        float jv = tanhf(gj);
        float fv = 1.f / (1.f + __expf(-gf));
        float ov = 1.f / (1.f + __expf(-go));
        float cn = creg[r] * fv + iv * jv;
        float hn = tanhf(cn) * ov;
        creg[r] = cn;
        // both lane-halves computed identical (cn,hn); pack pairs for u32 store
        union { _Float16 f; unsigned short s; } cv; cv.f = (_Float16)hn;
        u32 other = (u32)(unsigned short)__shfl_xor((int)cv.s, 1);
        size_t idx = (size_t)(rbase + r) * HID + hcol;
        if (owner) {
            if (outp) outp[idx] = hn;
            if (lh) { lh[idx] = hn; lc[idx] = cn; }
            if (!(c16 & 1)) {
                u32 pk = (u32)cv.s | (other << 16);
                __hip_atomic_store((u32*)(rw + idx), pk,
                                   __ATOMIC_RELAXED, __HIP_MEMORY_SCOPE_AGENT);
            }
        }
    }
}

// ---- fused two-layer pipelined persistent kernel ---------------------------
__global__ __launch_bounds__(256, 1) void lstm_fused(
    const _Float16* __restrict__ WhR0, const _Float16* __restrict__ WxR1,
    const _Float16* __restrict__ WhR1, const _Float16* __restrict__ Gc,
    const float* __restrict__ hinit, _Float16* __restrict__ ring,
    float* __restrict__ cb, float* __restrict__ out,
    const float* __restrict__ bias1, int t0, int nsteps, int nbar0)
{
    const int lane = threadIdx.x & 63;
    const int wave = threadIdx.x >> 6;
    const int g = blockIdx.x;
    const int c16 = lane & 15, quad = lane >> 4;
    const int hcol = g * 8 + (c16 & 7);
    const bool owner = (c16 < 8);
    const int rbase = wave * 16 + quad * 4;

    __shared__ half8 smw[4096];           // Wh1 block slice, 64 KiB
    __shared__ f32x4 red0[3][4][2][64];   // 24 KiB
    __shared__ f32x4 red1[3][4][2][64];   // 24 KiB

    _Float16* ring0 = ring;
    _Float16* ring1 = ring + 2 * SLSZ;
    const size_t FO = (size_t)SEQ * SLSZ;

    // Wh1 -> LDS (per-block slice is contiguous 32768 halfs)
    {
        const _Float16* wsrc = WhR1 + (size_t)g * 32768;
        for (int i = threadIdx.x; i < 4096; i += 256)
            smw[i] = *(const half8*)(wsrc + (size_t)i * 8);
    }

    // bh0, bx1 register-resident (128 VGPR)
    half8 bh0[2][8], bx1[2][8];
#pragma unroll
    for (int tau = 0; tau < 2; ++tau)
#pragma unroll
        for (int i = 0; i < 8; ++i) {
            size_t off = ((size_t)((g * 2 + tau) * 32 + wave * 8 + i) * 64 + lane) * 8;
            bh0[tau][i] = *(const half8*)(WhR0 + off);
            bx1[tau][i] = *(const half8*)(WxR1 + off);
        }

    float bv1[2];
#pragma unroll
    for (int tau = 0; tau < 2; ++tau)
        bv1[tau] = bias1[(tau * 2 + (c16 >> 3)) * 1024 + hcol];

    float creg0[4], creg1[4];
#pragma unroll
    for (int r = 0; r < 4; ++r) {
        creg0[r] = cb[(size_t)(rbase + r) * HID + hcol];
        creg1[r] = cb[SLSZ + (size_t)(rbase + r) * HID + hcol];
    }

    const int colG0 = (c16 >> 3) * 1024 + hcol;
    __syncthreads();  // smw ready

    for (int tl = 0; tl < nsteps; ++tl) {
        const int s  = t0 + tl;
        const int t1 = s - 1;
        const bool do0 = (s < SEQ);
        const bool do1 = (t1 >= 0);

        // acc inits + G0 prefetch (plain cached loads; Gc static per launch)
        f32x4 acc0[4][2], acc1[4][2];
#pragma unroll
        for (int m = 0; m < 4; ++m)
#pragma unroll
            for (int tau = 0; tau < 2; ++tau) {
                acc0[m][tau] = f32x4{0.f, 0.f, 0.f, 0.f};
                acc1[m][tau] = f32x4{0.f, 0.f, 0.f, 0.f};
            }
#pragma unroll
        for (int m = 0; m < 4; ++m)
            if (m == wave) {
                acc1[m][0] = f32x4{bv1[0], bv1[0], bv1[0], bv1[0]};
                acc1[m][1] = f32x4{bv1[1], bv1[1], bv1[1], bv1[1]};
            }
        if (do0) {
            const _Float16* Gt = Gc + (size_t)tl * 4 * SLSZ;
#pragma unroll
            for (int tau = 0; tau < 2; ++tau) {
                f32x4 v;
#pragma unroll
                for (int r = 0; r < 4; ++r)
                    v[r] = (float)Gt[(size_t)(rbase + r) * 4096 + tau * 2048 + colG0];
#pragma unroll
                for (int m = 0; m < 4; ++m)
                    if (m == wave) acc0[m][tau] = v;
            }
        }

        if (tl > 0) grid_barrier(nbar0 + tl);

        // pass A: shared A = h0[s-1] (or hinit at s==0)
        const _Float16* h0prev = ring0 + (size_t)((s - 1) & 1) * SLSZ;
        if (do0 && do1)
            passA<false, true, true>(acc0, acc1, h0prev, bh0, bx1, wave, c16, quad);
        else if (do0)   // s == 0
            passA<true, true, false>(acc0, acc1, hinit, bh0, bx1, wave, c16, quad);
        else            // s == SEQ (drain step)
            passA<false, false, true>(acc0, acc1, h0prev, bh0, bx1, wave, c16, quad);

        // pass B: A = h1[t1-1] (or hinit+SLSZ at t1==0), B = Wh1 (LDS)
        if (do1) {
            if (t1 == 0)
                passB<true>(acc1, hinit + SLSZ, smw, wave, c16, quad, lane);
            else
                passB<false>(acc1, ring1 + (size_t)((t1 - 1) & 1) * SLSZ, smw,
                             wave, c16, quad, lane);
        }

        // cross-wave K reduction (wave w finalizes m-tile w)
        if (do0) {
#pragma unroll
            for (int m = 0; m < 4; ++m)
                if (m != wave) {
                    int slot = wave - (wave > m ? 1 : 0);
#pragma unroll
                    for (int tau = 0; tau < 2; ++tau)
                        red0[slot][m][tau][lane] = acc0[m][tau];
                }
        }
        if (do1) {
#pragma unroll
            for (int m = 0; m < 4; ++m)
                if (m != wave) {
                    int slot = wave - (wave > m ? 1 : 0);
#pragma unroll
                    for (int tau = 0; tau < 2; ++tau)
                        red1[slot][m][tau][lane] = acc1[m][tau];
                }
        }
        f32x4 own0[2], own1[2];
        own0[0] = acc0[0][0]; own0[1] = acc0[0][1];
        own1[0] = acc1[0][0]; own1[1] = acc1[0][1];
#pragma unroll
        for (int m = 1; m < 4; ++m)
            if (wave == m) {
                own0[0] = acc0[m][0]; own0[1] = acc0[m][1];
                own1[0] = acc1[m][0]; own1[1] = acc1[m][1];
            }
        __syncthreads();

        // epilogues
        if (do0) {
            f32x4 fin[2];
#pragma unroll
            for (int tau = 0; tau < 2; ++tau) {
                f32x4 ssum = own0[tau];
#pragma unroll
                for (int v = 0; v < 3; ++v) ssum += red0[v][wave][tau][lane];
                fin[tau] = ssum;
            }
            float* lh = (s == SEQ - 1) ? out + FO : nullptr;
            float* lc = (s == SEQ - 1) ? out + FO + 2 * SLSZ : nullptr;
            cell_epilogue(fin, creg0, ring0 + (size_t)(s & 1) * SLSZ,
                          nullptr, lh, lc, rbase, hcol, c16, owner);
        }
        if (do1) {
            f32x4 fin[2];
#pragma unroll
            for (int tau = 0; tau < 2; ++tau) {
                f32x4 ssum = own1[tau];
#pragma unroll
                for (int v = 0; v < 3; ++v) ssum += red1[v][wave][tau][lane];
                fin[tau] = ssum;
            }
            float* lh = (t1 == SEQ - 1) ? out + FO + SLSZ : nullptr;
            float* lc = (t1 == SEQ - 1) ? out + FO + 3 * SLSZ : nullptr;
            cell_epilogue(fin, creg1, ring1 + (size_t)(t1 & 1) * SLSZ,
                          out + (size_t)t1 * SLSZ, lh, lc, rbase, hcol, c16, owner);
        }
    }

    // persist cell state for the next chunk (kernel-end flush covers this)
    if (owner) {
#pragma unroll
        for (int r = 0; r < 4; ++r) {
            cb[(size_t)(rbase + r) * HID + hcol] = creg0[r];
            cb[SLSZ + (size_t)(rbase + r) * HID + hcol] = creg1[r];
        }
    }
}

extern "C" void kernel_launch(void* const* d_in, const int* in_sizes, int n_in,
                              void* d_out, int out_size, void* d_ws, size_t ws_size,
                              hipStream_t stream) {
    const float* X  = (const float*)d_in[0];
    const float* h0 = (const float*)d_in[1];
    const float* c0 = (const float*)d_in[2];
    const float* W  = (const float*)d_in[3];
    const float* bb = (const float*)d_in[4];
    float* out = (float*)d_out;
    char* ws = (char*)d_ws;

    const size_t FIXED = 34603008ULL;
    int CH = 0;
    const int tiers[4] = {32, 16, 8, 4};
    for (int i = 0; i < 4; ++i)
        if (ws_size >= FIXED + (size_t)tiers[i] * 524288ULL) { CH = tiers[i]; break; }
    if (CH == 0) {
        zero_out<<<dim3(33024), 256, 0, stream>>>(out);
        return;
    }

    _Float16* WpX  = (_Float16*)(ws + 0);
    _Float16* WhR0 = (_Float16*)(ws + 8388608);
    _Float16* WxR1 = (_Float16*)(ws + 16777216);
    _Float16* WhR1 = (_Float16*)(ws + 25165824);
    _Float16* ring = (_Float16*)(ws + 33554432);
    float*    cb   = (float*)(ws + 34078720);
    _Float16* Gc   = (_Float16*)(ws + 34603008);

    const size_t MSTRIDE = 2048ULL * 4096ULL;   // per-layer W block (floats)
    const int MC = CH * BATCH;
    const int NCHUNK = SEQ / CH;

    pack1<<<dim3(256, 8), 256, 0, stream>>>(W, WpX);                             // Wx0
    pack_wh<<<dim3(NBLK, 8), 256, 0, stream>>>(W + 1024 * 4096, WhR0);           // Wh0
    pack_wh<<<dim3(NBLK, 8), 256, 0, stream>>>(W + MSTRIDE, WxR1);               // Wx1
    pack_wh<<<dim3(NBLK, 8), 256, 0, stream>>>(W + MSTRIDE + 1024 * 4096, WhR1); // Wh1
    copy_f4<<<dim3(128), 256, 0, stream>>>(c0, cb);
    init_bar_k<<<dim3(1), 256, 0, stream>>>();

    int nbar = 0;
    for (int chunk = 0; chunk < NCHUNK; ++chunk) {
        gemm_in<<<dim3(MC / 128, 32), 256, 0, stream>>>(
            X + (size_t)chunk * MC * 1024, WpX, bb, Gc);
        int nsteps = CH + (chunk == NCHUNK - 1 ? 1 : 0);
        lstm_fused<<<dim3(NBLK), 256, 0, stream>>>(
            WhR0, WxR1, WhR1, Gc, h0, ring, cb, out, bb + 4096,
            chunk * CH, nsteps, nbar);
        nbar += nsteps - 1;
    }
}

// Round 4
// 11199.059 us; speedup vs baseline: 1.7935x; 1.1449x over previous
//
#include <hip/hip_runtime.h>

// BasicLSTM on MI355X (gfx950) — single mega-kernel: persistent two-layer
// recurrence (128 consumer blocks) + concurrent input-GEMM producers
// (64 blocks), one launch for the whole sequence.
//
// Consumers: barrier-step s computes layer0 t=s and layer1 t=s-1 (513 steps).
// h exchange via MALL-coherent relaxed agent atomics (no per-step fences).
// Hierarchical barrier: 8 group counters -> global counter -> per-group
// replicated release flags; explicit vmcnt(0) drain before arrival.
// Producers: chunk c (CH steps) input GEMM X@Wx0+b0 -> Gc slot (c&1),
// written 2 chunks ahead, gated on consumers' done[c-2]; one release fence
// (wbL2) per chunk; consumers do one acquire fence (inv) per chunk.
//
// Weights: Wh0/Wx1 B-frags in 128 VGPR/wave; Wh1 in 64 KiB LDS; Wx0 std-pack
// read by producers. Cell state in registers for the entire sequence.
//
// Workspace (bytes):
//   WpX  @ 0        : Wx0 std pack                8,388,608
//   WhR0 @ 8388608  : Wh0 per-block frag pack     8,388,608
//   WxR1 @ 16777216 : Wx1 per-block frag pack     8,388,608
//   WhR1 @ 25165824 : Wh1 per-block frag pack     8,388,608
//   ring @ 33554432 : 2 layers x 2 slots x 64x1024 fp16   524,288
//   (pad)@ 34078720 : 524,288 (unused)
//   Gc   @ 34603008 : 2 slots x CH x 64x4096 fp16   2*CH*524,288
// FIXED = 34,603,008; CH=8 -> 42,991,616 (known-good ws floor); CH=4 tier.

typedef _Float16 half8 __attribute__((ext_vector_type(8)));
typedef float    f32x4 __attribute__((ext_vector_type(4)));
typedef unsigned long long u64;
typedef unsigned int u32;

#define SEQ 512
#define BATCH 64
#define HID 1024
#define NCONS 128
#define NPROD 64
#define SLSZ 65536  // BATCH*HID

// sync state (ints): [grp*64] arrive ctr (grp<8); [512] global ctr;
// [576+grp*64] release flags; [1088+c*16] ready ctr; [3136+c*16] done ctr.
__device__ int g_sync[8192];

__global__ void init_bar_k() {
    for (int i = threadIdx.x; i < 8192; i += 256) g_sync[i] = 0;
}

// ---- fallback: write zeros over all of d_out (guarantees >=1 launch) -------
__global__ void zero_out(float* __restrict__ out) {
    size_t i = (size_t)blockIdx.x * blockDim.x + threadIdx.x;
    ((f32x4*)out)[i] = f32x4{0.f, 0.f, 0.f, 0.f};
}

// ---- standard pack: 1024x4096 fp32 -> fp16 B-frags (for producer GEMM) -----
__global__ void pack1(const float* __restrict__ src, _Float16* __restrict__ dst) {
    int nt   = blockIdx.x;        // 0..255
    int ktg  = blockIdx.y;        // 0..7
    int lane = threadIdx.x & 63;
    int wave = threadIdx.x >> 6;
    int kt   = ktg * 4 + wave;    // 0..31
    int k0 = kt * 32 + (lane >> 4) * 8;
    int n  = nt * 16 + (lane & 15);
    half8 v;
#pragma unroll
    for (int j = 0; j < 8; ++j)
        v[j] = (_Float16)src[(size_t)(k0 + j) * 4096 + n];
    *(half8*)(dst + ((size_t)(nt * 32 + kt) * 64 + lane) * 8) = v;
}

// ---- per-block frag pack (consumer weights) --------------------------------
// Block g owns hid cols g*8..g*8+7; tau=0 covers gates {i,j}, tau=1 {f,o}.
__global__ void pack_wh(const float* __restrict__ src, _Float16* __restrict__ dst) {
    int g    = blockIdx.x;        // 0..127
    int ktg  = blockIdx.y;        // 0..7
    int lane = threadIdx.x & 63;
    int wave = threadIdx.x >> 6;
    int kt   = ktg * 4 + wave;    // 0..31
    int c16  = lane & 15;
    int k0   = kt * 32 + (lane >> 4) * 8;
#pragma unroll
    for (int tau = 0; tau < 2; ++tau) {
        int col = (tau * 2 + (c16 >> 3)) * 1024 + g * 8 + (c16 & 7);
        half8 v;
#pragma unroll
        for (int j = 0; j < 8; ++j)
            v[j] = (_Float16)src[(size_t)(k0 + j) * 4096 + col];
        *(half8*)(dst + ((size_t)((g * 2 + tau) * 32 + kt) * 64 + lane) * 8) = v;
    }
}

// ---- producer GEMM tile: 128x128 of G = A(fp32) @ WpX + bias -> fp16 -------
__device__ __forceinline__ void gemm_tile(
    const float* __restrict__ A, const _Float16* __restrict__ Bp,
    const float* __restrict__ bias, _Float16* __restrict__ Gout,
    int mi, int ni)
{
    int lane = threadIdx.x & 63;
    int wave = threadIdx.x >> 6;
    int wm = wave & 1, wn = wave >> 1;
    int m0 = mi * 128 + wm * 64;
    int n0 = ni * 128 + wn * 64;
    int col = lane & 15, quad = lane >> 4;
    f32x4 acc[4][4] = {};
    const float*    Arow  = A + (size_t)(m0 + col) * 1024 + quad * 8;
    const _Float16* Bbase = Bp + (size_t)(n0 >> 4) * 16384 + (size_t)lane * 8;
    for (int kt = 0; kt < 32; ++kt) {
        half8 a[4], b[4];
#pragma unroll
        for (int i = 0; i < 4; ++i) {
            const float* p = Arow + (size_t)i * 16 * 1024 + kt * 32;
            f32x4 v0 = *(const f32x4*)(p);
            f32x4 v1 = *(const f32x4*)(p + 4);
            a[i][0] = (_Float16)v0[0]; a[i][1] = (_Float16)v0[1];
            a[i][2] = (_Float16)v0[2]; a[i][3] = (_Float16)v0[3];
            a[i][4] = (_Float16)v1[0]; a[i][5] = (_Float16)v1[1];
            a[i][6] = (_Float16)v1[2]; a[i][7] = (_Float16)v1[3];
        }
#pragma unroll
        for (int j = 0; j < 4; ++j)
            b[j] = *(const half8*)(Bbase + (size_t)j * 16384 + kt * 512);
#pragma unroll
        for (int i = 0; i < 4; ++i)
#pragma unroll
            for (int j = 0; j < 4; ++j)
                acc[i][j] = __builtin_amdgcn_mfma_f32_16x16x32_f16(a[i], b[j], acc[i][j], 0, 0, 0);
    }
#pragma unroll
    for (int j = 0; j < 4; ++j) {
        int n = n0 + j * 16 + col;
        float bv = bias[n];
#pragma unroll
        for (int i = 0; i < 4; ++i)
#pragma unroll
            for (int r = 0; r < 4; ++r) {
                int m = m0 + i * 16 + quad * 4 + r;
                Gout[(size_t)m * 4096 + n] = (_Float16)(acc[i][j][r] + bv);
            }
    }
}

// ---- hierarchical grid barrier among NCONS consumer blocks -----------------
__device__ __forceinline__ void grid_barrier(int n, int grp) {
    asm volatile("s_waitcnt vmcnt(0)" ::: "memory");  // drain ring/out stores
    __syncthreads();
    if (threadIdx.x == 0) {
        int v = __hip_atomic_fetch_add(&g_sync[grp * 64], 1,
                                       __ATOMIC_RELAXED, __HIP_MEMORY_SCOPE_AGENT);
        if (v == n * (NCONS / 8) - 1) {   // last of my 16-block group
            int gv = __hip_atomic_fetch_add(&g_sync[512], 1,
                                            __ATOMIC_RELAXED, __HIP_MEMORY_SCOPE_AGENT);
            if (gv == n * 8 - 1) {        // last group: publish to all 8 flag lines
#pragma unroll
                for (int i = 0; i < 8; ++i)
                    __hip_atomic_store(&g_sync[576 + i * 64], n,
                                       __ATOMIC_RELAXED, __HIP_MEMORY_SCOPE_AGENT);
            }
        }
        while (__hip_atomic_load(&g_sync[576 + grp * 64],
                                 __ATOMIC_RELAXED, __HIP_MEMORY_SCOPE_AGENT) < n)
            __builtin_amdgcn_s_sleep(1);
    }
    __syncthreads();
}

// ---- coherent (cross-XCD) helpers ------------------------------------------
__device__ __forceinline__ half8 cload8(const _Float16* p) {
    union { half8 h; u64 u[2]; } x;
    x.u[0] = __hip_atomic_load((const u64*)p, __ATOMIC_RELAXED, __HIP_MEMORY_SCOPE_AGENT);
    x.u[1] = __hip_atomic_load((const u64*)p + 1, __ATOMIC_RELAXED, __HIP_MEMORY_SCOPE_AGENT);
    return x.h;
}

__device__ __forceinline__ half8 cvt_row(const float* p) {
    f32x4 v0 = *(const f32x4*)p, v1 = *(const f32x4*)(p + 4);
    half8 a;
    a[0] = (_Float16)v0[0]; a[1] = (_Float16)v0[1];
    a[2] = (_Float16)v0[2]; a[3] = (_Float16)v0[3];
    a[4] = (_Float16)v1[0]; a[5] = (_Float16)v1[1];
    a[6] = (_Float16)v1[2]; a[7] = (_Float16)v1[3];
    return a;
}

// ---- fused pass A: A = h0-source, feeds acc0 (bh0) and/or acc1 (bx1) -------
template <bool F32, bool DO0, bool DO1>
__device__ __forceinline__ void passA(
    f32x4 (&acc0)[4][2], f32x4 (&acc1)[4][2], const void* src,
    const half8 (&b0)[2][8], const half8 (&b1)[2][8],
    int wave, int c16, int quad)
{
#pragma unroll
    for (int i = 0; i < 8; ++i) {
        const int k0 = (wave * 8 + i) * 32 + quad * 8;
        half8 a[4];
#pragma unroll
        for (int m = 0; m < 4; ++m) {
            if constexpr (F32)
                a[m] = cvt_row((const float*)src + (size_t)(m * 16 + c16) * HID + k0);
            else
                a[m] = cload8((const _Float16*)src + (size_t)(m * 16 + c16) * HID + k0);
        }
#pragma unroll
        for (int m = 0; m < 4; ++m) {
            if constexpr (DO0) {
                acc0[m][0] = __builtin_amdgcn_mfma_f32_16x16x32_f16(a[m], b0[0][i], acc0[m][0], 0, 0, 0);
                acc0[m][1] = __builtin_amdgcn_mfma_f32_16x16x32_f16(a[m], b0[1][i], acc0[m][1], 0, 0, 0);
            }
            if constexpr (DO1) {
                acc1[m][0] = __builtin_amdgcn_mfma_f32_16x16x32_f16(a[m], b1[0][i], acc1[m][0], 0, 0, 0);
                acc1[m][1] = __builtin_amdgcn_mfma_f32_16x16x32_f16(a[m], b1[1][i], acc1[m][1], 0, 0, 0);
            }
        }
    }
}

// ---- pass B: A = h1-source, B = Wh1 from LDS, feeds acc1 -------------------
template <bool F32>
__device__ __forceinline__ void passB(
    f32x4 (&acc1)[4][2], const void* src, const half8* smw,
    int wave, int c16, int quad, int lane)
{
#pragma unroll
    for (int i = 0; i < 8; ++i) {
        const int k0 = (wave * 8 + i) * 32 + quad * 8;
        half8 a[4];
#pragma unroll
        for (int m = 0; m < 4; ++m) {
            if constexpr (F32)
                a[m] = cvt_row((const float*)src + (size_t)(m * 16 + c16) * HID + k0);
            else
                a[m] = cload8((const _Float16*)src + (size_t)(m * 16 + c16) * HID + k0);
        }
        half8 bw0 = smw[(size_t)((0 * 32 + wave * 8 + i) * 64 + lane)];
        half8 bw1 = smw[(size_t)((1 * 32 + wave * 8 + i) * 64 + lane)];
#pragma unroll
        for (int m = 0; m < 4; ++m) {
            acc1[m][0] = __builtin_amdgcn_mfma_f32_16x16x32_f16(a[m], bw0, acc1[m][0], 0, 0, 0);
            acc1[m][1] = __builtin_amdgcn_mfma_f32_16x16x32_f16(a[m], bw1, acc1[m][1], 0, 0, 0);
        }
    }
}

// ---- LSTM cell epilogue: gates -> (c,h), coherent packed ring store --------
__device__ __forceinline__ void cell_epilogue(
    const f32x4 (&fin)[2], float (&creg)[4], _Float16* rw, float* outp,
    float* lh, float* lc, int rbase, int hcol, int c16, bool owner)
{
#pragma unroll
    for (int r = 0; r < 4; ++r) {
        float v0 = fin[0][r], v1 = fin[1][r];
        float x0 = __shfl_xor(v0, 8), x1 = __shfl_xor(v1, 8);
        float gi = owner ? v0 : x0, gj = owner ? x0 : v0;
        float gf = owner ? v1 : x1, go = owner ? x1 : v1;
        float iv = 1.f / (1.f + __expf(-gi));
        float jv = tanhf(gj);
        float fv = 1.f / (1.f + __expf(-gf));
        float ov = 1.f / (1.f + __expf(-go));
        float cn = creg[r] * fv + iv * jv;
        float hn = tanhf(cn) * ov;
        creg[r] = cn;
        union { _Float16 f; unsigned short s; } cv; cv.f = (_Float16)hn;
        u32 other = (u32)(unsigned short)__shfl_xor((int)cv.s, 1);
        size_t idx = (size_t)(rbase + r) * HID + hcol;
        if (owner) {
            if (outp) outp[idx] = hn;
            if (lh) { lh[idx] = hn; lc[idx] = cn; }
            if (!(c16 & 1)) {
                u32 pk = (u32)cv.s | (other << 16);
                __hip_atomic_store((u32*)(rw + idx), pk,
                                   __ATOMIC_RELAXED, __HIP_MEMORY_SCOPE_AGENT);
            }
        }
    }
}

// ---- producer path: input GEMM chunks, 2 ahead of consumers ----------------
__device__ __forceinline__ void producer_path(
    const _Float16* __restrict__ WpX, const float* __restrict__ X,
    const float* __restrict__ bias0, _Float16* __restrict__ Gc,
    int nchunk, int ch)
{
    const int p = blockIdx.x;                    // 0..63
    const int rows = ch * 64;
    const int tpp = (rows / 128) * 32 / NPROD;   // 2 (ch=8) or 1 (ch=4)
    const size_t slotsz = (size_t)ch * 4 * SLSZ; // halfs
    for (int c = 0; c < nchunk; ++c) {
        if (c >= 2) {    // WAR: slot (c&1) free once consumers finished c-2
            if (threadIdx.x == 0)
                while (__hip_atomic_load(&g_sync[3136 + (c - 2) * 16],
                                         __ATOMIC_RELAXED, __HIP_MEMORY_SCOPE_AGENT) < NCONS)
                    __builtin_amdgcn_s_sleep(4);
            __syncthreads();
        }
        const float* A = X + (size_t)c * rows * 1024;
        _Float16* Gout = Gc + (size_t)(c & 1) * slotsz;
        for (int tt = 0; tt < tpp; ++tt) {
            int T = p * tpp + tt;
            gemm_tile(A, WpX, bias0, Gout, T >> 5, T & 31);
        }
        asm volatile("s_waitcnt vmcnt(0)" ::: "memory");  // all waves' stores in L2
        __syncthreads();
        if (threadIdx.x == 0) {
            __builtin_amdgcn_fence(__ATOMIC_RELEASE, "agent");  // wbL2 -> MALL
            __hip_atomic_fetch_add(&g_sync[1088 + c * 16], 1,
                                   __ATOMIC_RELAXED, __HIP_MEMORY_SCOPE_AGENT);
        }
        __syncthreads();
    }
}

// ---- consumer path: the two-layer pipelined recurrence ---------------------
__device__ __forceinline__ void consumer_path(
    int g, const _Float16* __restrict__ WhR0, const _Float16* __restrict__ WxR1,
    const _Float16* __restrict__ WhR1, const _Float16* __restrict__ Gc,
    const float* __restrict__ hinit, const float* __restrict__ cinit,
    _Float16* __restrict__ ring, float* __restrict__ out,
    const float* __restrict__ bias1, int ch)
{
    const int lane = threadIdx.x & 63;
    const int wave = threadIdx.x >> 6;
    const int c16 = lane & 15, quad = lane >> 4;
    const int hcol = g * 8 + (c16 & 7);
    const bool owner = (c16 < 8);
    const int rbase = wave * 16 + quad * 4;
    const int grp = g & 7;
    const size_t slotsz = (size_t)ch * 4 * SLSZ;

    __shared__ half8 smw[4096];           // Wh1 block slice, 64 KiB
    __shared__ f32x4 red0[3][4][2][64];   // 24 KiB
    __shared__ f32x4 red1[3][4][2][64];   // 24 KiB

    _Float16* ring0 = ring;
    _Float16* ring1 = ring + 2 * SLSZ;
    const size_t FO = (size_t)SEQ * SLSZ;

    // Wh1 -> LDS
    {
        const _Float16* wsrc = WhR1 + (size_t)g * 32768;
        for (int i = threadIdx.x; i < 4096; i += 256)
            smw[i] = *(const half8*)(wsrc + (size_t)i * 8);
    }
    // bh0, bx1 register-resident
    half8 bh0[2][8], bx1[2][8];
#pragma unroll
    for (int tau = 0; tau < 2; ++tau)
#pragma unroll
        for (int i = 0; i < 8; ++i) {
            size_t off = ((size_t)((g * 2 + tau) * 32 + wave * 8 + i) * 64 + lane) * 8;
            bh0[tau][i] = *(const half8*)(WhR0 + off);
            bx1[tau][i] = *(const half8*)(WxR1 + off);
        }
    float bv1[2];
#pragma unroll
    for (int tau = 0; tau < 2; ++tau)
        bv1[tau] = bias1[(tau * 2 + (c16 >> 3)) * 1024 + hcol];

    float creg0[4], creg1[4];
#pragma unroll
    for (int r = 0; r < 4; ++r) {
        creg0[r] = cinit[(size_t)(rbase + r) * HID + hcol];
        creg1[r] = cinit[SLSZ + (size_t)(rbase + r) * HID + hcol];
    }

    const int colG0 = (c16 >> 3) * 1024 + hcol;
    __syncthreads();  // smw ready

    for (int sidx = 0; sidx <= SEQ; ++sidx) {
        const int s = sidx, t1 = s - 1;
        const bool do0 = (s < SEQ), do1 = (t1 >= 0);
        int cchunk = 0, tl = 0;
        if (do0) { cchunk = s / ch; tl = s - cchunk * ch; }

        // chunk gate: wait for producers, then one acquire-inv for the chunk
        if (do0 && tl == 0) {
            if (threadIdx.x == 0) {
                while (__hip_atomic_load(&g_sync[1088 + cchunk * 16],
                                         __ATOMIC_RELAXED, __HIP_MEMORY_SCOPE_AGENT) < NPROD)
                    __builtin_amdgcn_s_sleep(1);
                __builtin_amdgcn_fence(__ATOMIC_ACQUIRE, "agent");  // inv
            }
            __syncthreads();
        }

        // acc inits + G prefetch (plain cached loads, slot stable this chunk)
        f32x4 acc0[4][2], acc1[4][2];
#pragma unroll
        for (int m = 0; m < 4; ++m)
#pragma unroll
            for (int tau = 0; tau < 2; ++tau) {
                acc0[m][tau] = f32x4{0.f, 0.f, 0.f, 0.f};
                acc1[m][tau] = f32x4{0.f, 0.f, 0.f, 0.f};
            }
#pragma unroll
        for (int m = 0; m < 4; ++m)
            if (m == wave) {
                acc1[m][0] = f32x4{bv1[0], bv1[0], bv1[0], bv1[0]};
                acc1[m][1] = f32x4{bv1[1], bv1[1], bv1[1], bv1[1]};
            }
        if (do0) {
            const _Float16* Gt = Gc + (size_t)(cchunk & 1) * slotsz + (size_t)tl * 4 * SLSZ;
#pragma unroll
            for (int tau = 0; tau < 2; ++tau) {
                f32x4 v;
#pragma unroll
                for (int r = 0; r < 4; ++r)
                    v[r] = (float)Gt[(size_t)(rbase + r) * 4096 + tau * 2048 + colG0];
#pragma unroll
                for (int m = 0; m < 4; ++m)
                    if (m == wave) acc0[m][tau] = v;
            }
        }

        if (sidx > 0) grid_barrier(sidx, grp);
        // after barrier: all consumers' G loads for the chunk's last step done
        if (do0 && tl == ch - 1 && threadIdx.x == 0)
            __hip_atomic_fetch_add(&g_sync[3136 + cchunk * 16], 1,
                                   __ATOMIC_RELAXED, __HIP_MEMORY_SCOPE_AGENT);

        // pass A: shared A = h0[s-1] (or hinit at s==0)
        const _Float16* h0prev = ring0 + (size_t)((s - 1) & 1) * SLSZ;
        if (do0 && do1)
            passA<false, true, true>(acc0, acc1, h0prev, bh0, bx1, wave, c16, quad);
        else if (do0)   // s == 0
            passA<true, true, false>(acc0, acc1, hinit, bh0, bx1, wave, c16, quad);
        else            // s == SEQ (drain)
            passA<false, false, true>(acc0, acc1, h0prev, bh0, bx1, wave, c16, quad);

        // pass B: A = h1[t1-1] (or hinit+SLSZ at t1==0), B = Wh1 (LDS)
        if (do1) {
            if (t1 == 0)
                passB<true>(acc1, hinit + SLSZ, smw, wave, c16, quad, lane);
            else
                passB<false>(acc1, ring1 + (size_t)((t1 - 1) & 1) * SLSZ, smw,
                             wave, c16, quad, lane);
        }

        // cross-wave K reduction (wave w finalizes m-tile w)
        if (do0) {
#pragma unroll
            for (int m = 0; m < 4; ++m)
                if (m != wave) {
                    int slot = wave - (wave > m ? 1 : 0);
#pragma unroll
                    for (int tau = 0; tau < 2; ++tau)
                        red0[slot][m][tau][lane] = acc0[m][tau];
                }
        }
        if (do1) {
#pragma unroll
            for (int m = 0; m < 4; ++m)
                if (m != wave) {
                    int slot = wave - (wave > m ? 1 : 0);
#pragma unroll
                    for (int tau = 0; tau < 2; ++tau)
                        red1[slot][m][tau][lane] = acc1[m][tau];
                }
        }
        f32x4 own0[2], own1[2];
        own0[0] = acc0[0][0]; own0[1] = acc0[0][1];
        own1[0] = acc1[0][0]; own1[1] = acc1[0][1];
#pragma unroll
        for (int m = 1; m < 4; ++m)
            if (wave == m) {
                own0[0] = acc0[m][0]; own0[1] = acc0[m][1];
                own1[0] = acc1[m][0]; own1[1] = acc1[m][1];
            }
        __syncthreads();

        // epilogues
        if (do0) {
            f32x4 fin[2];
#pragma unroll
            for (int tau = 0; tau < 2; ++tau) {
                f32x4 ssum = own0[tau];
#pragma unroll
                for (int v = 0; v < 3; ++v) ssum += red0[v][wave][tau][lane];
                fin[tau] = ssum;
            }
            float* lh = (s == SEQ - 1) ? out + FO : nullptr;
            float* lc = (s == SEQ - 1) ? out + FO + 2 * SLSZ : nullptr;
            cell_epilogue(fin, creg0, ring0 + (size_t)(s & 1) * SLSZ,
                          nullptr, lh, lc, rbase, hcol, c16, owner);
        }
        if (do1) {
            f32x4 fin[2];
#pragma unroll
            for (int tau = 0; tau < 2; ++tau) {
                f32x4 ssum = own1[tau];
#pragma unroll
                for (int v = 0; v < 3; ++v) ssum += red1[v][wave][tau][lane];
                fin[tau] = ssum;
            }
            float* lh = (t1 == SEQ - 1) ? out + FO + SLSZ : nullptr;
            float* lc = (t1 == SEQ - 1) ? out + FO + 3 * SLSZ : nullptr;
            cell_epilogue(fin, creg1, ring1 + (size_t)(t1 & 1) * SLSZ,
                          out + (size_t)t1 * SLSZ, lh, lc, rbase, hcol, c16, owner);
        }
    }
}

// ---- mega kernel: 64 producers + 128 consumers, one launch -----------------
__global__ __launch_bounds__(256, 1) void lstm_mega(
    const _Float16* __restrict__ WpX, const _Float16* __restrict__ WhR0,
    const _Float16* __restrict__ WxR1, const _Float16* __restrict__ WhR1,
    _Float16* __restrict__ Gc, const float* __restrict__ X,
    const float* __restrict__ hinit, const float* __restrict__ cinit,
    _Float16* __restrict__ ring, float* __restrict__ out,
    const float* __restrict__ bias0, const float* __restrict__ bias1,
    int nchunk, int ch)
{
    if (blockIdx.x < NPROD) {
        producer_path(WpX, X, bias0, Gc, nchunk, ch);
        return;
    }
    consumer_path((int)blockIdx.x - NPROD, WhR0, WxR1, WhR1, Gc,
                  hinit, cinit, ring, out, bias1, ch);
}

extern "C" void kernel_launch(void* const* d_in, const int* in_sizes, int n_in,
                              void* d_out, int out_size, void* d_ws, size_t ws_size,
                              hipStream_t stream) {
    const float* X  = (const float*)d_in[0];
    const float* h0 = (const float*)d_in[1];
    const float* c0 = (const float*)d_in[2];
    const float* W  = (const float*)d_in[3];
    const float* bb = (const float*)d_in[4];
    float* out = (float*)d_out;
    char* ws = (char*)d_ws;

    const size_t FIXED = 34603008ULL;
    int CH = 0;
    if (ws_size >= FIXED + 2ULL * 8 * 524288ULL)      CH = 8;   // 2 slots x 4 MB
    else if (ws_size >= FIXED + 2ULL * 4 * 524288ULL) CH = 4;   // 2 slots x 2 MB
    if (CH == 0) {
        zero_out<<<dim3(33024), 256, 0, stream>>>(out);
        return;
    }

    _Float16* WpX  = (_Float16*)(ws + 0);
    _Float16* WhR0 = (_Float16*)(ws + 8388608);
    _Float16* WxR1 = (_Float16*)(ws + 16777216);
    _Float16* WhR1 = (_Float16*)(ws + 25165824);
    _Float16* ring = (_Float16*)(ws + 33554432);
    _Float16* Gc   = (_Float16*)(ws + 34603008);

    const size_t MSTRIDE = 2048ULL * 4096ULL;   // per-layer W block (floats)

    pack1<<<dim3(256, 8), 256, 0, stream>>>(W, WpX);                             // Wx0
    pack_wh<<<dim3(NCONS, 8), 256, 0, stream>>>(W + 1024 * 4096, WhR0);          // Wh0
    pack_wh<<<dim3(NCONS, 8), 256, 0, stream>>>(W + MSTRIDE, WxR1);              // Wx1
    pack_wh<<<dim3(NCONS, 8), 256, 0, stream>>>(W + MSTRIDE + 1024 * 4096, WhR1);// Wh1
    init_bar_k<<<dim3(1), 256, 0, stream>>>();

    lstm_mega<<<dim3(NPROD + NCONS), 256, 0, stream>>>(
        WpX, WhR0, WxR1, WhR1, Gc, X, h0, c0, ring, out,
        bb, bb + 4096, SEQ / CH, CH);
}